// Round 1
// baseline (449.996 us; speedup 1.0000x reference)
//
#include <hip/hip_runtime.h>
#include <cstdint>

using u16 = unsigned short;
typedef __bf16 bf16x8 __attribute__((ext_vector_type(8)));
typedef float f32x4 __attribute__((ext_vector_type(4)));
typedef u16 u16x8 __attribute__((ext_vector_type(8)));
typedef u16 u16x4 __attribute__((ext_vector_type(4)));

#define DEV static __device__ __forceinline__

DEV u16 f2bf(float f) {
  uint32_t u = __builtin_bit_cast(uint32_t, f);
  u += 0x7FFFu + ((u >> 16) & 1u);
  return (u16)(u >> 16);
}
DEV float bf2f(u16 h) {
  uint32_t u = ((uint32_t)h) << 16;
  return __builtin_bit_cast(float, u);
}

#define MFMA(a, b, c) __builtin_amdgcn_mfma_f32_16x16x32_bf16((a), (b), (c), 0, 0, 0)

// ---------------------------------------------------------------------------
// Projection GEMM: C[m,n] = sum_k x[m,k] * W[n,k] + bias[n]   (x f32, W f32)
// M=8192, N=1024, K=1024. Output bf16 in head layout:
//   vtrans=0:  out[(b*16+h)*2048 + s][d]      (Q, K)
//   vtrans=1:  out[(b*16+h)*64 + d][s]        (V, transposed per head)
// 128x128 tile, BK=64, 4 waves (2x2), LDS stride 72 (2-way conflicts only).
// ---------------------------------------------------------------------------
__global__ __launch_bounds__(256) void proj_gemm(
    const float* __restrict__ x, const float* __restrict__ W,
    const float* __restrict__ bias, u16* __restrict__ out, int vtrans) {
  __shared__ u16 As[128][72];
  __shared__ u16 Bs[128][72];
  const int tid = threadIdx.x;
  const int m0 = blockIdx.y * 128, n0 = blockIdx.x * 128;
  const int w = tid >> 6, lane = tid & 63;
  const int wr = w >> 1, wc = w & 1;
  const int lr = lane & 15, lk = (lane >> 4) * 8;

  f32x4 acc[4][4];
  const f32x4 fzero = {0.f, 0.f, 0.f, 0.f};
#pragma unroll
  for (int m = 0; m < 4; ++m)
#pragma unroll
    for (int n = 0; n < 4; ++n) acc[m][n] = fzero;

  for (int kt = 0; kt < 16; ++kt) {
    const int k0 = kt * 64;
    __syncthreads();
#pragma unroll
    for (int c = 0; c < 8; ++c) {
      const int chunk = c * 256 + tid;
      const int row = chunk >> 4, c4 = chunk & 15;
      const float4 av = *(const float4*)(x + (size_t)(m0 + row) * 1024 + k0 + c4 * 4);
      const float4 bv = *(const float4*)(W + (size_t)(n0 + row) * 1024 + k0 + c4 * 4);
      u16x4 ah, bh;
      ah[0] = f2bf(av.x); ah[1] = f2bf(av.y); ah[2] = f2bf(av.z); ah[3] = f2bf(av.w);
      bh[0] = f2bf(bv.x); bh[1] = f2bf(bv.y); bh[2] = f2bf(bv.z); bh[3] = f2bf(bv.w);
      *(u16x4*)&As[row][c4 * 4] = ah;
      *(u16x4*)&Bs[row][c4 * 4] = bh;
    }
    __syncthreads();
#pragma unroll
    for (int kk = 0; kk < 2; ++kk) {
      bf16x8 a[4], b[4];
#pragma unroll
      for (int m = 0; m < 4; ++m)
        a[m] = *(const bf16x8*)&As[wr * 64 + m * 16 + lr][kk * 32 + lk];
#pragma unroll
      for (int n = 0; n < 4; ++n)
        b[n] = *(const bf16x8*)&Bs[wc * 64 + n * 16 + lr][kk * 32 + lk];
#pragma unroll
      for (int m = 0; m < 4; ++m)
#pragma unroll
        for (int n = 0; n < 4; ++n) acc[m][n] = MFMA(a[m], b[n], acc[m][n]);
    }
  }

#pragma unroll
  for (int n = 0; n < 4; ++n) {
    const int col = n0 + wc * 64 + n * 16 + lr;
    const float bv = bias[col];
    const int h = col >> 6, d = col & 63;
#pragma unroll
    for (int m = 0; m < 4; ++m) {
#pragma unroll
      for (int j = 0; j < 4; ++j) {
        const int rowg = m0 + wr * 64 + m * 16 + (lane >> 4) * 4 + j;
        const int bb = rowg >> 11, s = rowg & 2047;
        const float v = acc[m][n][j] + bv;
        size_t idx;
        if (!vtrans)
          idx = ((size_t)(bb * 16 + h) * 2048 + s) * 64 + d;
        else
          idx = ((size_t)(bb * 16 + h) * 64 + d) * 2048 + s;
        out[idx] = f2bf(v);
      }
    }
  }
}

// ---------------------------------------------------------------------------
// Flash attention: per (head, q-tile of 64). 4 waves x 16 q-rows.
// Q,K in [head][s][d] bf16; V in [head][d][s] bf16 (transposed).
// Online softmax in f32, logits kept in log2 domain (scale folded).
// Output: hi/lo bf16 split of attention output, layout [b*2048+s][h*64+d].
// ---------------------------------------------------------------------------
__global__ __launch_bounds__(256) void attn_fwd(
    const u16* __restrict__ Qh, const u16* __restrict__ Kh,
    const u16* __restrict__ Vt, u16* __restrict__ Ahi, u16* __restrict__ Alo) {
  __shared__ u16 Qs[64][72], Ks[64][72], Vs[64][72], Ps[64][72];
  const int tid = threadIdx.x;
  const int w = tid >> 6, lane = tid & 63;
  const int lr = lane & 15, lk = (lane >> 4) * 8;
  const int head = blockIdx.x, q0 = blockIdx.y * 64;
  const u16* Qb = Qh + (size_t)head * 131072;
  const u16* Kb = Kh + (size_t)head * 131072;
  const u16* Vb = Vt + (size_t)head * 131072;

#pragma unroll
  for (int c = 0; c < 2; ++c) {
    const int chunk = c * 256 + tid;
    const int row = chunk >> 3, c8 = chunk & 7;
    *(u16x8*)&Qs[row][c8 * 8] = *(const u16x8*)(Qb + (size_t)(q0 + row) * 64 + c8 * 8);
  }
  __syncthreads();
  bf16x8 aq[2];
  aq[0] = *(const bf16x8*)&Qs[w * 16 + lr][lk];
  aq[1] = *(const bf16x8*)&Qs[w * 16 + lr][32 + lk];

  const f32x4 fzero = {0.f, 0.f, 0.f, 0.f};
  f32x4 oacc[4];
#pragma unroll
  for (int nd = 0; nd < 4; ++nd) oacc[nd] = fzero;
  float mrow[4] = {-1e30f, -1e30f, -1e30f, -1e30f};
  float lrow[4] = {0.f, 0.f, 0.f, 0.f};

  for (int kt = 0; kt < 32; ++kt) {
    const int t0 = kt * 64;
    __syncthreads();
#pragma unroll
    for (int c = 0; c < 2; ++c) {
      const int chunk = c * 256 + tid;
      const int row = chunk >> 3, c8 = chunk & 7;
      *(u16x8*)&Ks[row][c8 * 8] = *(const u16x8*)(Kb + (size_t)(t0 + row) * 64 + c8 * 8);
      *(u16x8*)&Vs[row][c8 * 8] = *(const u16x8*)(Vb + (size_t)row * 2048 + t0 + c8 * 8);
    }
    __syncthreads();

    f32x4 sacc[4];
#pragma unroll
    for (int n = 0; n < 4; ++n) sacc[n] = fzero;
#pragma unroll
    for (int kk = 0; kk < 2; ++kk) {
#pragma unroll
      for (int n = 0; n < 4; ++n) {
        const bf16x8 bk = *(const bf16x8*)&Ks[n * 16 + lr][kk * 32 + lk];
        sacc[n] = MFMA(aq[kk], bk, sacc[n]);
      }
    }

    const float SC = 0.18033688011112042f;  // (1/8) * log2(e)
#pragma unroll
    for (int n = 0; n < 4; ++n)
#pragma unroll
      for (int j = 0; j < 4; ++j) sacc[n][j] *= SC;

    float alph[4], rs[4];
#pragma unroll
    for (int j = 0; j < 4; ++j) {
      float v = fmaxf(fmaxf(sacc[0][j], sacc[1][j]), fmaxf(sacc[2][j], sacc[3][j]));
      v = fmaxf(v, __shfl_xor(v, 1));
      v = fmaxf(v, __shfl_xor(v, 2));
      v = fmaxf(v, __shfl_xor(v, 4));
      v = fmaxf(v, __shfl_xor(v, 8));
      const float mn = fmaxf(mrow[j], v);
      alph[j] = exp2f(mrow[j] - mn);
      mrow[j] = mn;
      rs[j] = 0.f;
    }
#pragma unroll
    for (int n = 0; n < 4; ++n)
#pragma unroll
      for (int j = 0; j < 4; ++j) {
        const float p = exp2f(sacc[n][j] - mrow[j]);
        sacc[n][j] = p;
        rs[j] += p;
      }
#pragma unroll
    for (int j = 0; j < 4; ++j) {
      float r = rs[j];
      r += __shfl_xor(r, 1);
      r += __shfl_xor(r, 2);
      r += __shfl_xor(r, 4);
      r += __shfl_xor(r, 8);
      lrow[j] = lrow[j] * alph[j] + r;
    }
#pragma unroll
    for (int nd = 0; nd < 4; ++nd)
#pragma unroll
      for (int j = 0; j < 4; ++j) oacc[nd][j] *= alph[j];

    const int prow = w * 16 + (lane >> 4) * 4;
#pragma unroll
    for (int n = 0; n < 4; ++n)
#pragma unroll
      for (int j = 0; j < 4; ++j) Ps[prow + j][n * 16 + lr] = f2bf(sacc[n][j]);

#pragma unroll
    for (int kk = 0; kk < 2; ++kk) {
      const bf16x8 pa = *(const bf16x8*)&Ps[w * 16 + lr][kk * 32 + lk];
#pragma unroll
      for (int nd = 0; nd < 4; ++nd) {
        const bf16x8 bvf = *(const bf16x8*)&Vs[nd * 16 + lr][kk * 32 + lk];
        oacc[nd] = MFMA(pa, bvf, oacc[nd]);
      }
    }
  }

  const int b = head >> 4, h = head & 15;
#pragma unroll
  for (int nd = 0; nd < 4; ++nd)
#pragma unroll
    for (int j = 0; j < 4; ++j) {
      const float v = oacc[nd][j] / lrow[j];
      const int qg = q0 + w * 16 + (lane >> 4) * 4 + j;
      const int d = nd * 16 + lr;
      const size_t idx = ((size_t)(b * 2048 + qg)) * 1024 + h * 64 + d;
      const u16 hi = f2bf(v);
      Ahi[idx] = hi;
      Alo[idx] = f2bf(v - bf2f(hi));
    }
}

// ---------------------------------------------------------------------------
// Output GEMM, split-bf16 (3-product): out = (Ahi+Alo) @ Wo^T + bo  (f32 out)
// M=8192, N=1024, K=1024, BK=32. LDS stride 40.
// ---------------------------------------------------------------------------
__global__ __launch_bounds__(256) void out_gemm(
    const u16* __restrict__ Ahi, const u16* __restrict__ Alo,
    const float* __restrict__ Wo, const float* __restrict__ bo,
    float* __restrict__ out) {
  __shared__ u16 AsH[128][40], AsL[128][40], BsH[128][40], BsL[128][40];
  const int tid = threadIdx.x;
  const int m0 = blockIdx.y * 128, n0 = blockIdx.x * 128;
  const int w = tid >> 6, lane = tid & 63;
  const int wr = w >> 1, wc = w & 1;
  const int lr = lane & 15, lk = (lane >> 4) * 8;

  f32x4 acc[4][4];
  const f32x4 fzero = {0.f, 0.f, 0.f, 0.f};
#pragma unroll
  for (int m = 0; m < 4; ++m)
#pragma unroll
    for (int n = 0; n < 4; ++n) acc[m][n] = fzero;

  for (int kt = 0; kt < 32; ++kt) {
    const int k0 = kt * 32;
    __syncthreads();
#pragma unroll
    for (int c = 0; c < 2; ++c) {
      const int chunk = c * 256 + tid;
      const int row = chunk >> 2, c8 = chunk & 3;
      *(u16x8*)&AsH[row][c8 * 8] = *(const u16x8*)(Ahi + (size_t)(m0 + row) * 1024 + k0 + c8 * 8);
      *(u16x8*)&AsL[row][c8 * 8] = *(const u16x8*)(Alo + (size_t)(m0 + row) * 1024 + k0 + c8 * 8);
    }
#pragma unroll
    for (int c = 0; c < 4; ++c) {
      const int chunk = c * 256 + tid;
      const int row = chunk >> 3, c4 = chunk & 7;
      const float4 wv = *(const float4*)(Wo + (size_t)(n0 + row) * 1024 + k0 + c4 * 4);
      u16x4 hv, lv;
      hv[0] = f2bf(wv.x); lv[0] = f2bf(wv.x - bf2f(hv[0]));
      hv[1] = f2bf(wv.y); lv[1] = f2bf(wv.y - bf2f(hv[1]));
      hv[2] = f2bf(wv.z); lv[2] = f2bf(wv.z - bf2f(hv[2]));
      hv[3] = f2bf(wv.w); lv[3] = f2bf(wv.w - bf2f(hv[3]));
      *(u16x4*)&BsH[row][c4 * 4] = hv;
      *(u16x4*)&BsL[row][c4 * 4] = lv;
    }
    __syncthreads();
    bf16x8 ah[4], al[4], bh[4], bl[4];
#pragma unroll
    for (int m = 0; m < 4; ++m) {
      ah[m] = *(const bf16x8*)&AsH[wr * 64 + m * 16 + lr][lk];
      al[m] = *(const bf16x8*)&AsL[wr * 64 + m * 16 + lr][lk];
    }
#pragma unroll
    for (int n = 0; n < 4; ++n) {
      bh[n] = *(const bf16x8*)&BsH[wc * 64 + n * 16 + lr][lk];
      bl[n] = *(const bf16x8*)&BsL[wc * 64 + n * 16 + lr][lk];
    }
#pragma unroll
    for (int m = 0; m < 4; ++m)
#pragma unroll
      for (int n = 0; n < 4; ++n) {
        acc[m][n] = MFMA(ah[m], bh[n], acc[m][n]);
        acc[m][n] = MFMA(al[m], bh[n], acc[m][n]);
        acc[m][n] = MFMA(ah[m], bl[n], acc[m][n]);
      }
  }

#pragma unroll
  for (int n = 0; n < 4; ++n) {
    const int col = n0 + wc * 64 + n * 16 + lr;
    const float bv = bo[col];
#pragma unroll
    for (int m = 0; m < 4; ++m)
#pragma unroll
      for (int j = 0; j < 4; ++j) {
        const int rowg = m0 + wr * 64 + m * 16 + (lane >> 4) * 4 + j;
        out[(size_t)rowg * 1024 + col] = acc[m][n][j] + bv;
      }
  }
}

// ---------------------------------------------------------------------------
extern "C" void kernel_launch(void* const* d_in, const int* in_sizes, int n_in,
                              void* d_out, int out_size, void* d_ws, size_t ws_size,
                              hipStream_t stream) {
  const float* q  = (const float*)d_in[0];
  const float* k  = (const float*)d_in[1];
  const float* v  = (const float*)d_in[2];
  const float* Wq = (const float*)d_in[3];
  const float* bq = (const float*)d_in[4];
  const float* Wk = (const float*)d_in[5];
  const float* bk = (const float*)d_in[6];
  const float* Wv = (const float*)d_in[7];
  const float* bv = (const float*)d_in[8];
  const float* Wo = (const float*)d_in[9];
  const float* bo = (const float*)d_in[10];

  // Workspace layout (bf16 elements), 5 regions x 8388608 elems = 83.9 MB.
  u16* ws  = (u16*)d_ws;
  u16* Qh  = ws;
  u16* Kh  = ws + (size_t)8388608;
  u16* Vt  = ws + (size_t)16777216;
  u16* Ahi = ws + (size_t)25165824;
  u16* Alo = ws + (size_t)33554432;

  dim3 blk(256);
  proj_gemm<<<dim3(8, 64), blk, 0, stream>>>(q, Wq, bq, Qh, 0);
  proj_gemm<<<dim3(8, 64), blk, 0, stream>>>(k, Wk, bk, Kh, 0);
  proj_gemm<<<dim3(8, 64), blk, 0, stream>>>(v, Wv, bv, Vt, 1);
  attn_fwd<<<dim3(64, 32), blk, 0, stream>>>(Qh, Kh, Vt, Ahi, Alo);
  out_gemm<<<dim3(8, 64), blk, 0, stream>>>(Ahi, Alo, Wo, bo, (float*)d_out);
}

// Round 2
// 326.273 us; speedup vs baseline: 1.3792x; 1.3792x over previous
//
#include <hip/hip_runtime.h>
#include <cstdint>

using u16 = unsigned short;
using u32 = unsigned int;
typedef __bf16 bf16x8 __attribute__((ext_vector_type(8)));
typedef float f32x4 __attribute__((ext_vector_type(4)));
typedef float f32x16 __attribute__((ext_vector_type(16)));
typedef u16 u16x8 __attribute__((ext_vector_type(8)));
typedef u16 u16x4 __attribute__((ext_vector_type(4)));

#define DEV static __device__ __forceinline__

DEV u16 f2bf(float f) {
  uint32_t u = __builtin_bit_cast(uint32_t, f);
  u += 0x7FFFu + ((u >> 16) & 1u);
  return (u16)(u >> 16);
}
DEV float bf2f(u16 h) {
  uint32_t u = ((uint32_t)h) << 16;
  return __builtin_bit_cast(float, u);
}

#define MFMA(a, b, c) __builtin_amdgcn_mfma_f32_16x16x32_bf16((a), (b), (c), 0, 0, 0)
#define MFMA32(a, b, c) __builtin_amdgcn_mfma_f32_32x32x16_bf16((a), (b), (c), 0, 0, 0)

// ---------------------------------------------------------------------------
// Projection GEMM: C[m,n] = (sum_k x[m,k] * W[n,k] + bias[n]) * oscale
// M=8192, N=1024, K=1024. Output bf16 in head layout:
//   vtrans=0:  out[(b*16+h)*2048 + s][d]      (Q, K)
//   vtrans=1:  out[(b*16+h)*64 + d][s]        (V, transposed per head)
// Q projection folds in oscale = (1/8)*log2(e) so attn works in log2 domain.
// ---------------------------------------------------------------------------
__global__ __launch_bounds__(256) void proj_gemm(
    const float* __restrict__ x, const float* __restrict__ W,
    const float* __restrict__ bias, u16* __restrict__ out, int vtrans,
    float oscale) {
  __shared__ u16 As[128][72];
  __shared__ u16 Bs[128][72];
  const int tid = threadIdx.x;
  const int m0 = blockIdx.y * 128, n0 = blockIdx.x * 128;
  const int w = tid >> 6, lane = tid & 63;
  const int wr = w >> 1, wc = w & 1;
  const int lr = lane & 15, lk = (lane >> 4) * 8;

  f32x4 acc[4][4];
  const f32x4 fzero = {0.f, 0.f, 0.f, 0.f};
#pragma unroll
  for (int m = 0; m < 4; ++m)
#pragma unroll
    for (int n = 0; n < 4; ++n) acc[m][n] = fzero;

  for (int kt = 0; kt < 16; ++kt) {
    const int k0 = kt * 64;
    __syncthreads();
#pragma unroll
    for (int c = 0; c < 8; ++c) {
      const int chunk = c * 256 + tid;
      const int row = chunk >> 4, c4 = chunk & 15;
      const float4 av = *(const float4*)(x + (size_t)(m0 + row) * 1024 + k0 + c4 * 4);
      const float4 bv = *(const float4*)(W + (size_t)(n0 + row) * 1024 + k0 + c4 * 4);
      u16x4 ah, bh;
      ah[0] = f2bf(av.x); ah[1] = f2bf(av.y); ah[2] = f2bf(av.z); ah[3] = f2bf(av.w);
      bh[0] = f2bf(bv.x); bh[1] = f2bf(bv.y); bh[2] = f2bf(bv.z); bh[3] = f2bf(bv.w);
      *(u16x4*)&As[row][c4 * 4] = ah;
      *(u16x4*)&Bs[row][c4 * 4] = bh;
    }
    __syncthreads();
#pragma unroll
    for (int kk = 0; kk < 2; ++kk) {
      bf16x8 a[4], b[4];
#pragma unroll
      for (int m = 0; m < 4; ++m)
        a[m] = *(const bf16x8*)&As[wr * 64 + m * 16 + lr][kk * 32 + lk];
#pragma unroll
      for (int n = 0; n < 4; ++n)
        b[n] = *(const bf16x8*)&Bs[wc * 64 + n * 16 + lr][kk * 32 + lk];
#pragma unroll
      for (int m = 0; m < 4; ++m)
#pragma unroll
        for (int n = 0; n < 4; ++n) acc[m][n] = MFMA(a[m], b[n], acc[m][n]);
    }
  }

#pragma unroll
  for (int n = 0; n < 4; ++n) {
    const int col = n0 + wc * 64 + n * 16 + lr;
    const float bv = bias[col];
    const int h = col >> 6, d = col & 63;
#pragma unroll
    for (int m = 0; m < 4; ++m) {
#pragma unroll
      for (int j = 0; j < 4; ++j) {
        const int rowg = m0 + wr * 64 + m * 16 + (lane >> 4) * 4 + j;
        const int bb = rowg >> 11, s = rowg & 2047;
        const float v = (acc[m][n][j] + bv) * oscale;
        size_t idx;
        if (!vtrans)
          idx = ((size_t)(bb * 16 + h) * 2048 + s) * 64 + d;
        else
          idx = ((size_t)(bb * 16 + h) * 64 + d) * 2048 + s;
        out[idx] = f2bf(v);
      }
    }
  }
}

// ---------------------------------------------------------------------------
// Flash attention, 32x32 swapped-QK^T structure.
// Per block: 4 waves x 32 q-rows = 128 q. KV tiles of 64.
// Q pre-scaled by (1/8)*log2(e) -> scores are directly log2-domain.
// Swapped QK^T (A=K, B=Q): lane owns q = lane&31; scores for 32 k per tile
// live in 16 regs: k = (r&3) + 8*(r>>2) + 4*(lane>>5).
// Softmax fully in-register (1 shfl per reduce); defer-max THR=8.
// P -> PV A-fragments via v_cvt_pk_bf16_f32 + v_permlane32_swap_b32 (no LDS).
// Output: hi/lo bf16 split, layout [b*2048+s][h*64+d].
// ---------------------------------------------------------------------------
__global__ __launch_bounds__(256, 3) void attn_fwd(
    const u16* __restrict__ Qh, const u16* __restrict__ Kh,
    const u16* __restrict__ Vt, u16* __restrict__ Ahi, u16* __restrict__ Alo) {
  __shared__ u16 Ks[64][72];
  __shared__ u16 Vs[64][72];
  const int tid = threadIdx.x;
  const int w = tid >> 6, lane = tid & 63;
  const int lq = lane & 31, h = lane >> 5;
  const int head = blockIdx.x, q0 = blockIdx.y * 128;
  const u16* Qb = Qh + (size_t)head * 131072;
  const u16* Kb = Kh + (size_t)head * 131072;
  const u16* Vb = Vt + (size_t)head * 131072;
  const int qrow = q0 + w * 32 + lq;

  // Q fragments in registers: B-operand, lane holds Q[qrow][dc*16 + h*8 + 0..7]
  bf16x8 qf[4];
#pragma unroll
  for (int dc = 0; dc < 4; ++dc)
    qf[dc] = *(const bf16x8*)(Qb + (size_t)qrow * 64 + dc * 16 + h * 8);

  f32x16 o0 = {}, o1 = {};
  float m = -1e30f, lsum = 0.f;

  const int srow = tid >> 3, scol = (tid & 7) * 8;
  uint4 kr0, kr1, vr0, vr1;
  kr0 = *(const uint4*)(Kb + (size_t)srow * 64 + scol);
  kr1 = *(const uint4*)(Kb + (size_t)(32 + srow) * 64 + scol);
  vr0 = *(const uint4*)(Vb + (size_t)srow * 2048 + scol);
  vr1 = *(const uint4*)(Vb + (size_t)(32 + srow) * 2048 + scol);

  for (int kt = 0; kt < 32; ++kt) {
    __syncthreads();
    *(uint4*)&Ks[srow][scol] = kr0;
    *(uint4*)&Ks[32 + srow][scol] = kr1;
    *(uint4*)&Vs[srow][scol] = vr0;
    *(uint4*)&Vs[32 + srow][scol] = vr1;
    __syncthreads();
    if (kt + 1 < 32) {
      const int t0n = (kt + 1) * 64;
      kr0 = *(const uint4*)(Kb + (size_t)(t0n + srow) * 64 + scol);
      kr1 = *(const uint4*)(Kb + (size_t)(t0n + 32 + srow) * 64 + scol);
      vr0 = *(const uint4*)(Vb + (size_t)srow * 2048 + t0n + scol);
      vr1 = *(const uint4*)(Vb + (size_t)(32 + srow) * 2048 + t0n + scol);
    }

    // QK^T: two 32x32 tiles (k 0..31 and 32..63), sum over d via 4 chunks.
    f32x16 s0 = {}, s1 = {};
#pragma unroll
    for (int dc = 0; dc < 4; ++dc) {
      const bf16x8 k0 = *(const bf16x8*)&Ks[lq][dc * 16 + h * 8];
      const bf16x8 k1 = *(const bf16x8*)&Ks[32 + lq][dc * 16 + h * 8];
      s0 = MFMA32(k0, qf[dc], s0);
      s1 = MFMA32(k1, qf[dc], s1);
    }

    // Row max (lane-local + 1 shfl across halves)
    float pm = s0[0];
#pragma unroll
    for (int r = 1; r < 16; ++r) pm = fmaxf(pm, s0[r]);
#pragma unroll
    for (int r = 0; r < 16; ++r) pm = fmaxf(pm, s1[r]);
    pm = fmaxf(pm, __shfl_xor(pm, 32));

    // Defer-max rescale (THR = 8 in log2 units -> P bounded by 256)
    if (!__all(pm - m <= 8.0f)) {
      const float mn = fmaxf(m, pm);
      const float al = exp2f(m - mn);
      m = mn;
      lsum *= al;
#pragma unroll
      for (int r = 0; r < 16; ++r) {
        const float ar = __shfl(al, (r & 3) + 8 * (r >> 2) + 4 * h);
        o0[r] *= ar;
        o1[r] *= ar;
      }
    }

    float rs = 0.f;
#pragma unroll
    for (int r = 0; r < 16; ++r) {
      const float p = exp2f(s0[r] - m);
      s0[r] = p;
      rs += p;
    }
#pragma unroll
    for (int r = 0; r < 16; ++r) {
      const float p = exp2f(s1[r] - m);
      s1[r] = p;
      rs += p;
    }
    rs += __shfl_xor(rs, 32);
    lsum += rs;

    // Pack P to bf16 dwords: w[b*2+e] holds k = 8b + 4h + 2e + {0,1}
    u32 w0[8], w1[8];
#pragma unroll
    for (int b = 0; b < 4; ++b)
#pragma unroll
      for (int e = 0; e < 2; ++e) {
        asm("v_cvt_pk_bf16_f32 %0, %1, %2"
            : "=v"(w0[b * 2 + e]) : "v"(s0[4 * b + 2 * e]), "v"(s0[4 * b + 2 * e + 1]));
        asm("v_cvt_pk_bf16_f32 %0, %1, %2"
            : "=v"(w1[b * 2 + e]) : "v"(s1[4 * b + 2 * e]), "v"(s1[4 * b + 2 * e + 1]));
      }

    // permlane32_swap assembles PV A-fragments: chunk c needs
    // [own w[2c+h][0], own w[2c+h][1], partner w[2c+h][0], partner w[2c+h][1]]
    bf16x8 pa[4];
#pragma unroll
    for (int c = 0; c < 2; ++c) {
      u32 a0 = w0[(2 * c) * 2 + 0], b0 = w0[(2 * c + 1) * 2 + 0];
      u32 a1 = w0[(2 * c) * 2 + 1], b1 = w0[(2 * c + 1) * 2 + 1];
      asm("v_permlane32_swap_b32 %0, %1" : "+v"(a0), "+v"(b0));
      asm("v_permlane32_swap_b32 %0, %1" : "+v"(a1), "+v"(b1));
      const uint4 f = {a0, a1, b0, b1};
      pa[c] = __builtin_bit_cast(bf16x8, f);
    }
#pragma unroll
    for (int c = 0; c < 2; ++c) {
      u32 a0 = w1[(2 * c) * 2 + 0], b0 = w1[(2 * c + 1) * 2 + 0];
      u32 a1 = w1[(2 * c) * 2 + 1], b1 = w1[(2 * c + 1) * 2 + 1];
      asm("v_permlane32_swap_b32 %0, %1" : "+v"(a0), "+v"(b0));
      asm("v_permlane32_swap_b32 %0, %1" : "+v"(a1), "+v"(b1));
      const uint4 f = {a0, a1, b0, b1};
      pa[2 + c] = __builtin_bit_cast(bf16x8, f);
    }

    // PV: O[q][d], A=P (rows=q), B=V^T tile (cols=d, k=t)
#pragma unroll
    for (int c = 0; c < 4; ++c) {
      const bf16x8 v0f = *(const bf16x8*)&Vs[lq][c * 16 + h * 8];
      const bf16x8 v1f = *(const bf16x8*)&Vs[32 + lq][c * 16 + h * 8];
      o0 = MFMA32(pa[c], v0f, o0);
      o1 = MFMA32(pa[c], v1f, o1);
    }
  }

  // Epilogue: divide by row-sum, write hi/lo bf16 split.
  const int bb = head >> 4, hh = head & 15;
  const float linv = 1.0f / lsum;
#pragma unroll
  for (int r = 0; r < 16; ++r) {
    const int qr = (r & 3) + 8 * (r >> 2) + 4 * h;
    const float li = __shfl(linv, qr);
    const int qg = q0 + w * 32 + qr;
    const size_t base = ((size_t)(bb * 2048 + qg)) * 1024 + hh * 64;
    const float v0v = o0[r] * li;
    const u16 h0 = f2bf(v0v);
    Ahi[base + lq] = h0;
    Alo[base + lq] = f2bf(v0v - bf2f(h0));
    const float v1v = o1[r] * li;
    const u16 h1 = f2bf(v1v);
    Ahi[base + 32 + lq] = h1;
    Alo[base + 32 + lq] = f2bf(v1v - bf2f(h1));
  }
}

// ---------------------------------------------------------------------------
// Output GEMM, split-bf16 (3-product): out = (Ahi+Alo) @ Wo^T + bo  (f32 out)
// ---------------------------------------------------------------------------
__global__ __launch_bounds__(256) void out_gemm(
    const u16* __restrict__ Ahi, const u16* __restrict__ Alo,
    const float* __restrict__ Wo, const float* __restrict__ bo,
    float* __restrict__ out) {
  __shared__ u16 AsH[128][40], AsL[128][40], BsH[128][40], BsL[128][40];
  const int tid = threadIdx.x;
  const int m0 = blockIdx.y * 128, n0 = blockIdx.x * 128;
  const int w = tid >> 6, lane = tid & 63;
  const int wr = w >> 1, wc = w & 1;
  const int lr = lane & 15, lk = (lane >> 4) * 8;

  f32x4 acc[4][4];
  const f32x4 fzero = {0.f, 0.f, 0.f, 0.f};
#pragma unroll
  for (int m = 0; m < 4; ++m)
#pragma unroll
    for (int n = 0; n < 4; ++n) acc[m][n] = fzero;

  for (int kt = 0; kt < 32; ++kt) {
    const int k0 = kt * 32;
    __syncthreads();
#pragma unroll
    for (int c = 0; c < 2; ++c) {
      const int chunk = c * 256 + tid;
      const int row = chunk >> 2, c8 = chunk & 3;
      *(u16x8*)&AsH[row][c8 * 8] = *(const u16x8*)(Ahi + (size_t)(m0 + row) * 1024 + k0 + c8 * 8);
      *(u16x8*)&AsL[row][c8 * 8] = *(const u16x8*)(Alo + (size_t)(m0 + row) * 1024 + k0 + c8 * 8);
    }
#pragma unroll
    for (int c = 0; c < 4; ++c) {
      const int chunk = c * 256 + tid;
      const int row = chunk >> 3, c4 = chunk & 7;
      const float4 wv = *(const float4*)(Wo + (size_t)(n0 + row) * 1024 + k0 + c4 * 4);
      u16x4 hv, lv;
      hv[0] = f2bf(wv.x); lv[0] = f2bf(wv.x - bf2f(hv[0]));
      hv[1] = f2bf(wv.y); lv[1] = f2bf(wv.y - bf2f(hv[1]));
      hv[2] = f2bf(wv.z); lv[2] = f2bf(wv.z - bf2f(hv[2]));
      hv[3] = f2bf(wv.w); lv[3] = f2bf(wv.w - bf2f(hv[3]));
      *(u16x4*)&BsH[row][c4 * 4] = hv;
      *(u16x4*)&BsL[row][c4 * 4] = lv;
    }
    __syncthreads();
    bf16x8 ah[4], al[4], bh[4], bl[4];
#pragma unroll
    for (int m = 0; m < 4; ++m) {
      ah[m] = *(const bf16x8*)&AsH[wr * 64 + m * 16 + lr][lk];
      al[m] = *(const bf16x8*)&AsL[wr * 64 + m * 16 + lr][lk];
    }
#pragma unroll
    for (int n = 0; n < 4; ++n) {
      bh[n] = *(const bf16x8*)&BsH[wc * 64 + n * 16 + lr][lk];
      bl[n] = *(const bf16x8*)&BsL[wc * 64 + n * 16 + lr][lk];
    }
#pragma unroll
    for (int m = 0; m < 4; ++m)
#pragma unroll
      for (int n = 0; n < 4; ++n) {
        acc[m][n] = MFMA(ah[m], bh[n], acc[m][n]);
        acc[m][n] = MFMA(al[m], bh[n], acc[m][n]);
        acc[m][n] = MFMA(ah[m], bl[n], acc[m][n]);
      }
  }

#pragma unroll
  for (int n = 0; n < 4; ++n) {
    const int col = n0 + wc * 64 + n * 16 + lr;
    const float bv = bo[col];
#pragma unroll
    for (int m = 0; m < 4; ++m)
#pragma unroll
      for (int j = 0; j < 4; ++j) {
        const int rowg = m0 + wr * 64 + m * 16 + (lane >> 4) * 4 + j;
        out[(size_t)rowg * 1024 + col] = acc[m][n][j] + bv;
      }
  }
}

// ---------------------------------------------------------------------------
extern "C" void kernel_launch(void* const* d_in, const int* in_sizes, int n_in,
                              void* d_out, int out_size, void* d_ws, size_t ws_size,
                              hipStream_t stream) {
  const float* q  = (const float*)d_in[0];
  const float* k  = (const float*)d_in[1];
  const float* v  = (const float*)d_in[2];
  const float* Wq = (const float*)d_in[3];
  const float* bq = (const float*)d_in[4];
  const float* Wk = (const float*)d_in[5];
  const float* bk = (const float*)d_in[6];
  const float* Wv = (const float*)d_in[7];
  const float* bv = (const float*)d_in[8];
  const float* Wo = (const float*)d_in[9];
  const float* bo = (const float*)d_in[10];

  u16* ws  = (u16*)d_ws;
  u16* Qh  = ws;
  u16* Kh  = ws + (size_t)8388608;
  u16* Vt  = ws + (size_t)16777216;
  u16* Ahi = ws + (size_t)25165824;
  u16* Alo = ws + (size_t)33554432;

  const float SC = 0.18033688011112042f;  // (1/8) * log2(e)
  dim3 blk(256);
  proj_gemm<<<dim3(8, 64), blk, 0, stream>>>(q, Wq, bq, Qh, 0, SC);
  proj_gemm<<<dim3(8, 64), blk, 0, stream>>>(k, Wk, bk, Kh, 0, 1.0f);
  proj_gemm<<<dim3(8, 64), blk, 0, stream>>>(v, Wv, bv, Vt, 1, 1.0f);
  attn_fwd<<<dim3(64, 16), blk, 0, stream>>>(Qh, Kh, Vt, Ahi, Alo);
  out_gemm<<<dim3(8, 64), blk, 0, stream>>>(Ahi, Alo, Wo, bo, (float*)d_out);
}